// Round 1
// baseline (404.833 us; speedup 1.0000x reference)
//
#include <hip/hip_runtime.h>
#include <cstdint>
#include <cstddef>

// Problem constants (from reference): T=8192 tokens, E=64 experts, D=2048, capacity=256
#define T_TOK 8192
#define NE    64
#define ND    2048
#define CAP   256

#define BT 64   // tokens per GEMM block
#define BK 64   // K-tile

// ---------------------------------------------------------------- zero fill
__global__ __launch_bounds__(256) void k_zero(float4* __restrict__ o4, long n4,
                                              float* __restrict__ o, long n) {
  long i = (long)blockIdx.x * blockDim.x + threadIdx.x;
  long stride = (long)gridDim.x * blockDim.x;
  const float4 z = make_float4(0.f, 0.f, 0.f, 0.f);
  for (; i < n4; i += stride) o4[i] = z;
  if (blockIdx.x == 0 && threadIdx.x == 0) {
    for (long j = n4 * 4; j < n; ++j) o[j] = 0.f;  // tail (out_size % 4)
  }
}

// ------------------------------------------------- logits GEMM + gate epilogue
// grid: 128 blocks x 256 threads. Block computes logits tile [64 tok][64 exp]
// in fp32 (exactness matters for argmax), then fused softmax/argmax epilogue.
__global__ __launch_bounds__(256) void k_gate(
    const float* __restrict__ x, const float* __restrict__ wg,
    const float* __restrict__ gum,
    int* __restrict__ idx1o, int* __restrict__ idx2o,
    float* __restrict__ g1o, float* __restrict__ g2o,
    float* __restrict__ meb) {
  __shared__ float xs[BK][BT + 4];    // [k][token], stride 68 (16B-aligned rows)
  __shared__ float wsh[BK][NE + 4];   // [k][expert]
  __shared__ float lg[BT][NE + 4];    // logits tile
  __shared__ float mred[4][NE];

  const int tid = threadIdx.x;
  const int t0 = blockIdx.x * BT;
  const int ty = tid >> 4;   // token group 0..15 (4 tokens each)
  const int tx = tid & 15;   // expert group 0..15 (4 experts each)

  float acc[4][4];
#pragma unroll
  for (int i = 0; i < 4; ++i)
#pragma unroll
    for (int j = 0; j < 4; ++j) acc[i][j] = 0.f;

  for (int kt = 0; kt < ND; kt += BK) {
    // stage: 64 rows x 16 float4-chunks for both x-tile and wg-tile
#pragma unroll
    for (int i = 0; i < 4; ++i) {
      int s = tid + i * 256;
      int r = s >> 4;             // row 0..63 (token or expert)
      int c = (s & 15) << 2;      // k offset within tile
      float4 vx = *reinterpret_cast<const float4*>(x + (size_t)(t0 + r) * ND + kt + c);
      xs[c + 0][r] = vx.x; xs[c + 1][r] = vx.y; xs[c + 2][r] = vx.z; xs[c + 3][r] = vx.w;
      float4 vw = *reinterpret_cast<const float4*>(wg + (size_t)r * ND + kt + c);
      wsh[c + 0][r] = vw.x; wsh[c + 1][r] = vw.y; wsh[c + 2][r] = vw.z; wsh[c + 3][r] = vw.w;
    }
    __syncthreads();
#pragma unroll 8
    for (int k = 0; k < BK; ++k) {
      float4 a = *reinterpret_cast<const float4*>(&xs[k][ty << 2]);
      float4 b = *reinterpret_cast<const float4*>(&wsh[k][tx << 2]);
      float av[4] = {a.x, a.y, a.z, a.w};
      float bv[4] = {b.x, b.y, b.z, b.w};
#pragma unroll
      for (int i = 0; i < 4; ++i)
#pragma unroll
        for (int j = 0; j < 4; ++j) acc[i][j] = fmaf(av[i], bv[j], acc[i][j]);
    }
    __syncthreads();
  }

  // dump logits to LDS
#pragma unroll
  for (int i = 0; i < 4; ++i)
#pragma unroll
    for (int j = 0; j < 4; ++j) lg[(ty << 2) + i][(tx << 2) + j] = acc[i][j];
  __syncthreads();

  // epilogue: one wave handles 16 tokens; lane = expert
  const int wave = tid >> 6;
  const int lane = tid & 63;
  float meacc = 0.f;
  for (int tt = wave * 16; tt < wave * 16 + 16; ++tt) {
    const int t = t0 + tt;
    const float logit = lg[tt][lane];
    // softmax (wave64 reduce)
    float m = logit;
#pragma unroll
    for (int o = 32; o; o >>= 1) m = fmaxf(m, __shfl_xor(m, o));
    const float ex = expf(logit - m);
    float s = ex;
#pragma unroll
    for (int o = 32; o; o >>= 1) s += __shfl_xor(s, o);
    const float gate = ex / s;
    meacc += gate;
    // argmax over logits (first-index tie-break, matches jnp.argmax)
    float v1 = logit; int i1 = lane;
#pragma unroll
    for (int o = 32; o; o >>= 1) {
      float vv = __shfl_xor(v1, o); int jj = __shfl_xor(i1, o);
      if (vv > v1 || (vv == v1 && jj < i1)) { v1 = vv; i1 = jj; }
    }
    // second expert: argmax over logits+gumbel with top-1 masked
    float v2 = (lane == i1) ? -__builtin_inff() : logit + gum[(size_t)t * NE + lane];
    int i2 = lane;
#pragma unroll
    for (int o = 32; o; o >>= 1) {
      float vv = __shfl_xor(v2, o); int jj = __shfl_xor(i2, o);
      if (vv > v2 || (vv == v2 && jj < i2)) { v2 = vv; i2 = jj; }
    }
    const float gv1 = __shfl(gate, i1);
    const float gv2 = __shfl(gate, i2);
    if (lane == 0) {
      idx1o[t] = i1; idx2o[t] = i2; g1o[t] = gv1; g2o[t] = gv2;
    }
  }
  mred[wave][lane] = meacc;
  __syncthreads();
  if (wave == 0) {
    float sm = mred[0][lane] + mred[1][lane] + mred[2][lane] + mred[3][lane];
    meb[(size_t)blockIdx.x * NE + lane] = sm;  // per-block sum of gates per expert
  }
}

// ------------------------------------------------- per-expert token-order scan
// grid: 64 blocks (one per expert) x 256 threads, 32 tokens each.
__global__ __launch_bounds__(256) void k_scan(
    const int* __restrict__ idx1, const int* __restrict__ idx2,
    int* __restrict__ loc1, int* __restrict__ loc2, int* __restrict__ cnt1) {
  const int e = blockIdx.x;
  const int tid = threadIdx.x;
  const int base = tid * 32;
  int c1 = 0, c2 = 0;
  for (int i = 0; i < 32; ++i) {
    c1 += (idx1[base + i] == e);
    c2 += (idx2[base + i] == e);
  }
  const int lane = tid & 63, wave = tid >> 6;
  int s1 = c1, s2 = c2;
#pragma unroll
  for (int o = 1; o < 64; o <<= 1) {
    int t1 = __shfl_up(s1, o), t2 = __shfl_up(s2, o);
    if (lane >= o) { s1 += t1; s2 += t2; }
  }
  __shared__ int wt1[4], wt2[4];
  if (lane == 63) { wt1[wave] = s1; wt2[wave] = s2; }
  __syncthreads();
  int off1 = 0, off2 = 0, tot1 = 0;
#pragma unroll
  for (int w = 0; w < 4; ++w) {
    tot1 += wt1[w];
    if (w < wave) { off1 += wt1[w]; off2 += wt2[w]; }
  }
  int p1 = off1 + s1 - c1;          // exclusive prefix (token rank within expert)
  int p2 = off2 + s2 - c2 + tot1;   // + cnt1[e] offset per reference
  for (int i = 0; i < 32; ++i) {
    if (idx1[base + i] == e) loc1[base + i] = p1++;
    if (idx2[base + i] == e) loc2[base + i] = p2++;
  }
  if (tid == 0) cnt1[e] = tot1;
}

// ------------------------------------------------- scatter combine/dispatch
__global__ __launch_bounds__(256) void k_scatter(
    const int* __restrict__ idx1, const int* __restrict__ idx2,
    const float* __restrict__ g1, const float* __restrict__ g2,
    const int* __restrict__ loc1, const int* __restrict__ loc2,
    float* __restrict__ out) {
  const int t = blockIdx.x * 256 + threadIdx.x;
  if (t >= T_TOK) return;
  const int l1 = loc1[t], l2 = loc2[t];
  const bool k1 = l1 < CAP, k2 = l2 < CAP;
  const float a = k1 ? g1[t] : 0.f;
  const float b = k2 ? g2[t] : 0.f;
  const float denom = fmaxf(a + b, 1.1920929e-07f);  // finfo(f32).eps
  float* cw = out + 1;
  float* dm = out + 1 + (size_t)T_TOK * NE * CAP;
  if (k1) {
    size_t o = ((size_t)t * NE + idx1[t]) * CAP + l1;
    cw[o] = a / denom; dm[o] = 1.0f;
  }
  if (k2) {
    size_t o = ((size_t)t * NE + idx2[t]) * CAP + l2;
    cw[o] = b / denom; dm[o] = 1.0f;
  }
}

// ------------------------------------------------- l_aux
__global__ __launch_bounds__(64) void k_laux(const float* __restrict__ meb,
                                             const int* __restrict__ cnt1,
                                             float* __restrict__ out) {
  const int lane = threadIdx.x;  // 64 threads = 64 experts
  float ms = 0.f;
  for (int b = 0; b < 128; ++b) ms += meb[(size_t)b * NE + lane];
  const float me = ms / (float)T_TOK;
  const float ce = (float)cnt1[lane] / (float)T_TOK;
  float v = me * ce;
#pragma unroll
  for (int o = 32; o; o >>= 1) v += __shfl_xor(v, o);
  if (lane == 0) out[0] = v * (float)NE;  // mean(me*ce)*E*E = sum*E
}

// ---------------------------------------------------------------- launcher
extern "C" void kernel_launch(void* const* d_in, const int* in_sizes, int n_in,
                              void* d_out, int out_size, void* d_ws, size_t ws_size,
                              hipStream_t stream) {
  const float* x   = (const float*)d_in[0];   // [8192, 2048]
  const float* wg  = (const float*)d_in[1];   // [64, 2048]
  const float* gum = (const float*)d_in[2];   // [8192, 64]
  float* out = (float*)d_out;                 // [1 + T*E*C + T*E*C]

  // workspace layout (~230 KB)
  char* ws = (char*)d_ws;
  int*   idx1 = (int*)(ws + 0);
  int*   idx2 = (int*)(ws + 32768);
  float* g1   = (float*)(ws + 65536);
  float* g2   = (float*)(ws + 98304);
  int*   loc1 = (int*)(ws + 131072);
  int*   loc2 = (int*)(ws + 163840);
  int*   cnt1 = (int*)(ws + 196608);
  float* meb  = (float*)(ws + 197120);        // [128][64]

  const long n  = (long)out_size;   // 268,435,457 floats
  const long n4 = n >> 2;

  k_zero<<<dim3(2048), dim3(256), 0, stream>>>((float4*)out, n4, out, n);
  k_gate<<<dim3(T_TOK / BT), dim3(256), 0, stream>>>(x, wg, gum, idx1, idx2, g1, g2, meb);
  k_scan<<<dim3(NE), dim3(256), 0, stream>>>(idx1, idx2, loc1, loc2, cnt1);
  k_scatter<<<dim3(T_TOK / 256), dim3(256), 0, stream>>>(idx1, idx2, g1, g2, loc1, loc2, out);
  k_laux<<<dim3(1), dim3(64), 0, stream>>>(meb, cnt1, out);
}

// Round 2
// 299.231 us; speedup vs baseline: 1.3529x; 1.3529x over previous
//
#include <hip/hip_runtime.h>
#include <cstdint>
#include <cstddef>

// T=8192 tokens, E=64 experts, D=2048, capacity=2*ceil(T/E)=256
#define T_TOK 8192
#define NE    64
#define ND    2048
#define CAP   256

#define BT 64    // tokens per GEMM tile
#define BK 64    // K-tile
#define GB 256   // gate blocks = 128 token-tiles x 2 K-halves
#define ZB 2048  // zero blocks

// ---------------------------------------------------- fused zero + gate GEMM
// blocks [0,GB): split-K logits GEMM partials (fp32 exactness for argmax)
// blocks [GB, GB+ZB): grid-stride float4 zero of d_out
__global__ __launch_bounds__(256) void k_fused(
    const float* __restrict__ x, const float* __restrict__ wg,
    float* __restrict__ lp,            // [2][T_TOK][NE] partial logits
    float4* __restrict__ o4, long n4, float* __restrict__ o, long n) {
  __shared__ float xs[BK][BT + 4];     // [k][token], row stride 68 (16B aligned)
  __shared__ float wsh[BK][NE + 4];    // [k][expert]

  if (blockIdx.x < GB) {
    const int tid = threadIdx.x;
    const int tb = blockIdx.x >> 1;    // token tile 0..127
    const int kb = blockIdx.x & 1;     // K half 0..1
    const int t0 = tb * BT;
    const int k0 = kb * (ND / 2);
    const int ty = tid >> 4;           // token group (4 tokens)
    const int tx = tid & 15;           // expert group (4 experts)

    float acc[4][4];
#pragma unroll
    for (int i = 0; i < 4; ++i)
#pragma unroll
      for (int j = 0; j < 4; ++j) acc[i][j] = 0.f;

    for (int kt = k0; kt < k0 + ND / 2; kt += BK) {
#pragma unroll
      for (int i = 0; i < 4; ++i) {
        int s = tid + i * 256;
        int r = s >> 4;                // row 0..63 (token or expert)
        int c = (s & 15) << 2;         // k offset within tile
        float4 vx = *reinterpret_cast<const float4*>(x + (size_t)(t0 + r) * ND + kt + c);
        xs[c + 0][r] = vx.x; xs[c + 1][r] = vx.y; xs[c + 2][r] = vx.z; xs[c + 3][r] = vx.w;
        float4 vw = *reinterpret_cast<const float4*>(wg + (size_t)r * ND + kt + c);
        wsh[c + 0][r] = vw.x; wsh[c + 1][r] = vw.y; wsh[c + 2][r] = vw.z; wsh[c + 3][r] = vw.w;
      }
      __syncthreads();
#pragma unroll 8
      for (int k = 0; k < BK; ++k) {
        float4 a = *reinterpret_cast<const float4*>(&xs[k][ty << 2]);
        float4 b = *reinterpret_cast<const float4*>(&wsh[k][tx << 2]);
        float av[4] = {a.x, a.y, a.z, a.w};
        float bv[4] = {b.x, b.y, b.z, b.w};
#pragma unroll
        for (int i = 0; i < 4; ++i)
#pragma unroll
          for (int j = 0; j < 4; ++j) acc[i][j] = fmaf(av[i], bv[j], acc[i][j]);
      }
      __syncthreads();
    }
    // write partial logits [kb][t][e], float4 per row
    float* dst = lp + (size_t)kb * T_TOK * NE;
#pragma unroll
    for (int i = 0; i < 4; ++i) {
      float4 v = make_float4(acc[i][0], acc[i][1], acc[i][2], acc[i][3]);
      *reinterpret_cast<float4*>(dst + (size_t)(t0 + (ty << 2) + i) * NE + (tx << 2)) = v;
    }
  } else {
    // zero-fill branch
    long i = (long)(blockIdx.x - GB) * 256 + threadIdx.x;
    const long stride = (long)ZB * 256;
    const float4 z = make_float4(0.f, 0.f, 0.f, 0.f);
    for (; i < n4; i += stride) o4[i] = z;
    if (blockIdx.x == GB && threadIdx.x == 0) {
      for (long j = n4 * 4; j < n; ++j) o[j] = 0.f;  // odd tail element
    }
  }
}

// ------------------------------------------------- epilogue: softmax/argmax
// 128 blocks x 256 threads; one wave = 16 tokens; lane = expert.
__global__ __launch_bounds__(256) void k_epi(
    const float* __restrict__ lp, const float* __restrict__ gum,
    int* __restrict__ idx1o, int* __restrict__ idx2o,
    float* __restrict__ g1o, float* __restrict__ g2o,
    float* __restrict__ meb) {
  __shared__ float mred[4][NE];
  const int tid = threadIdx.x;
  const int wave = tid >> 6;
  const int lane = tid & 63;
  const int t0 = blockIdx.x * 64;
  float meacc = 0.f;
  for (int tt = wave * 16; tt < wave * 16 + 16; ++tt) {
    const int t = t0 + tt;
    const float logit = lp[(size_t)t * NE + lane] +
                        lp[(size_t)(T_TOK + t) * NE + lane];
    // softmax across the wave (lane = expert)
    float m = logit;
#pragma unroll
    for (int o = 32; o; o >>= 1) m = fmaxf(m, __shfl_xor(m, o));
    const float ex = expf(logit - m);
    float s = ex;
#pragma unroll
    for (int o = 32; o; o >>= 1) s += __shfl_xor(s, o);
    const float gate = ex / s;
    meacc += gate;
    // argmax over logits (first-index tie-break)
    float v1 = logit; int i1 = lane;
#pragma unroll
    for (int o = 32; o; o >>= 1) {
      float vv = __shfl_xor(v1, o); int jj = __shfl_xor(i1, o);
      if (vv > v1 || (vv == v1 && jj < i1)) { v1 = vv; i1 = jj; }
    }
    // second expert: gumbel-noised logits, top-1 masked
    float v2 = (lane == i1) ? -__builtin_inff() : logit + gum[(size_t)t * NE + lane];
    int i2 = lane;
#pragma unroll
    for (int o = 32; o; o >>= 1) {
      float vv = __shfl_xor(v2, o); int jj = __shfl_xor(i2, o);
      if (vv > v2 || (vv == v2 && jj < i2)) { v2 = vv; i2 = jj; }
    }
    const float gv1 = __shfl(gate, i1);
    const float gv2 = __shfl(gate, i2);
    if (lane == 0) {
      idx1o[t] = i1; idx2o[t] = i2; g1o[t] = gv1; g2o[t] = gv2;
    }
  }
  mred[wave][lane] = meacc;
  __syncthreads();
  if (wave == 0) {
    float sm = mred[0][lane] + mred[1][lane] + mred[2][lane] + mred[3][lane];
    meb[(size_t)blockIdx.x * NE + lane] = sm;
  }
}

// ------------------------------------------------- per-expert token scan
__global__ __launch_bounds__(256) void k_scan(
    const int* __restrict__ idx1, const int* __restrict__ idx2,
    int* __restrict__ loc1, int* __restrict__ loc2, int* __restrict__ cnt1) {
  const int e = blockIdx.x;
  const int tid = threadIdx.x;
  const int base = tid * 32;
  int c1 = 0, c2 = 0;
  for (int i = 0; i < 32; ++i) {
    c1 += (idx1[base + i] == e);
    c2 += (idx2[base + i] == e);
  }
  const int lane = tid & 63, wave = tid >> 6;
  int s1 = c1, s2 = c2;
#pragma unroll
  for (int o = 1; o < 64; o <<= 1) {
    int t1 = __shfl_up(s1, o), t2 = __shfl_up(s2, o);
    if (lane >= o) { s1 += t1; s2 += t2; }
  }
  __shared__ int wt1[4], wt2[4];
  if (lane == 63) { wt1[wave] = s1; wt2[wave] = s2; }
  __syncthreads();
  int off1 = 0, off2 = 0, tot1 = 0;
#pragma unroll
  for (int w = 0; w < 4; ++w) {
    tot1 += wt1[w];
    if (w < wave) { off1 += wt1[w]; off2 += wt2[w]; }
  }
  int p1 = off1 + s1 - c1;          // exclusive prefix = token rank in expert
  int p2 = off2 + s2 - c2 + tot1;   // + sum(mask1[:,e]) per reference
  for (int i = 0; i < 32; ++i) {
    if (idx1[base + i] == e) loc1[base + i] = p1++;
    if (idx2[base + i] == e) loc2[base + i] = p2++;
  }
  if (tid == 0) cnt1[e] = tot1;
}

// ------------------------------------- scatter combine/dispatch + l_aux
__global__ __launch_bounds__(256) void k_scat(
    const int* __restrict__ idx1, const int* __restrict__ idx2,
    const float* __restrict__ g1, const float* __restrict__ g2,
    const int* __restrict__ loc1, const int* __restrict__ loc2,
    const float* __restrict__ meb, const int* __restrict__ cnt1,
    float* __restrict__ out) {
  if (blockIdx.x == T_TOK / 256) {
    // l_aux block
    const int lane = threadIdx.x;
    if (lane >= 64) return;
    float ms = 0.f;
    for (int b = 0; b < 128; ++b) ms += meb[(size_t)b * NE + lane];
    const float me = ms / (float)T_TOK;
    const float ce = (float)cnt1[lane] / (float)T_TOK;
    float v = me * ce;
#pragma unroll
    for (int o = 32; o; o >>= 1) v += __shfl_xor(v, o);
    if (lane == 0) out[0] = v * (float)NE;  // mean(me*ce)*E*E = sum*E
    return;
  }
  const int t = blockIdx.x * 256 + threadIdx.x;
  const int l1 = loc1[t], l2 = loc2[t];
  const bool k1 = l1 < CAP, k2 = l2 < CAP;
  const float a = k1 ? g1[t] : 0.f;
  const float b = k2 ? g2[t] : 0.f;
  const float denom = fmaxf(a + b, 1.1920929e-07f);  // finfo(f32).eps
  float* cw = out + 1;
  float* dm = out + 1 + (size_t)T_TOK * NE * CAP;
  if (k1) {
    size_t o = ((size_t)t * NE + idx1[t]) * CAP + l1;
    cw[o] = a / denom; dm[o] = 1.0f;
  }
  if (k2) {
    size_t o = ((size_t)t * NE + idx2[t]) * CAP + l2;
    cw[o] = b / denom; dm[o] = 1.0f;
  }
}

// ---------------------------------------------------------------- launcher
extern "C" void kernel_launch(void* const* d_in, const int* in_sizes, int n_in,
                              void* d_out, int out_size, void* d_ws, size_t ws_size,
                              hipStream_t stream) {
  const float* x   = (const float*)d_in[0];   // [8192, 2048]
  const float* wg  = (const float*)d_in[1];   // [64, 2048]
  const float* gum = (const float*)d_in[2];   // [8192, 64]
  float* out = (float*)d_out;

  // workspace layout (~4.5 MB)
  char* ws = (char*)d_ws;
  float* lp   = (float*)(ws + 0);             // [2][8192][64] = 4 MB
  int*   idx1 = (int*)(ws + 4194304);
  int*   idx2 = (int*)(ws + 4227072);
  float* g1   = (float*)(ws + 4259840);
  float* g2   = (float*)(ws + 4292608);
  int*   loc1 = (int*)(ws + 4325376);
  int*   loc2 = (int*)(ws + 4358144);
  int*   cnt1 = (int*)(ws + 4390912);
  float* meb  = (float*)(ws + 4391168);       // [128][64]

  const long n  = (long)out_size;             // 268,435,457 floats
  const long n4 = n >> 2;

  k_fused<<<dim3(GB + ZB), dim3(256), 0, stream>>>(x, wg, lp, (float4*)out, n4, out, n);
  k_epi<<<dim3(T_TOK / 64), dim3(256), 0, stream>>>(lp, gum, idx1, idx2, g1, g2, meb);
  k_scan<<<dim3(NE), dim3(256), 0, stream>>>(idx1, idx2, loc1, loc2, cnt1);
  k_scat<<<dim3(T_TOK / 256 + 1), dim3(256), 0, stream>>>(idx1, idx2, g1, g2, loc1, loc2, meb, cnt1, out);
}